// Round 6
// baseline (1561.501 us; speedup 1.0000x reference)
//
#include <hip/hip_runtime.h>
#include <hip/hip_bf16.h>

// GAT 2-layer, MI355X. fp32 inputs. Split-bf16 MFMA GEMM1 with fused alpha
// epilogue (fp32-exact logits); CSR-by-dst aggregation, one wave per dst.
// 2-level bucket sort (dst>>7) kills fill_csr's 15x write amplification:
// bucket-major scatter (sequential per-bucket fill, L2-resident lines) then
// per-bucket CSR build with LDS histogram/scan/cursors.
// R6: every derived index clamped (scatter p, bucket, histogram, cursors, agg
// gathers) so no code path can read/write OOB — two consecutive container
// deaths were fault-shaped; with clamps a bad assumption degrades to a
// diagnosable absmax failure instead of a GPU page fault.

typedef __attribute__((ext_vector_type(8))) short short8;
typedef __attribute__((ext_vector_type(4))) short short4v;
typedef __attribute__((ext_vector_type(4))) float float4v;

#define NEG_SLOPE 0.2f

static __device__ __forceinline__ short f2bf(float v){
    union { float f; unsigned u; } x; x.f = v;
    unsigned r = x.u + 0x7fffu + ((x.u >> 16) & 1u);   // RNE
    return (short)(r >> 16);
}
static __device__ __forceinline__ float bf2f(short s){
    union { unsigned u; float f; } x; x.u = ((unsigned)(unsigned short)s) << 16;
    return x.f;
}

// ---------- W1 pack: fp32 [512][64] -> bf16 hi/lo, transposed [64][512] ----------
__global__ void pack_w1(const float* __restrict__ W1, short* __restrict__ Whi, short* __restrict__ Wlo){
    int i = blockIdx.x*blockDim.x + threadIdx.x;       // 64*512
    if (i >= 64*512) return;
    int n = i >> 9, k = i & 511;
    float w = W1[k*64 + n];
    short h = f2bf(w);
    Whi[i] = h;
    Wlo[i] = f2bf(w - bf2f(h));
}

// ---------- edge_index int64-layout probe: all odd words zero => int64 ----------
__global__ void detect_i64(const int* __restrict__ ei, int* __restrict__ flag, int E){
    __shared__ int any;
    if (threadIdx.x == 0) any = 0;
    __syncthreads();
    long stride = (2L*E) / 1024; if (stride < 2) stride = 2;
    long idx = (long)threadIdx.x * stride + 1;          // odd indices only
    if (idx < 2L*E && ei[idx] != 0) atomicAdd(&any, 1);
    __syncthreads();
    if (threadIdx.x == 0) flag[0] = (any == 0) ? 1 : 0; // 1 => int64 layout
}

// ---------- layer-1 GEMM: h1 = x @ W1 (split-bf16 MFMA) + alpha epilogue ----------
__global__ __launch_bounds__(256) void gemm1(const float* __restrict__ x,
        const short* __restrict__ Whi, const short* __restrict__ Wlo,
        const float* __restrict__ aS1, const float* __restrict__ aD1,
        short* __restrict__ h1b, float* __restrict__ as1, float* __restrict__ ad1, int N){
    int wave = threadIdx.x >> 6, lane = threadIdx.x & 63;
    int m = lane & 15, q = lane >> 4;
    int rowbase = blockIdx.x*64 + wave*16;
    int arow = rowbase + m; if (arow > N-1) arow = N-1;   // clamp; store guarded
    const float4* ap4 = (const float4*)(x + (size_t)arow*512 + q*8);
    float4v acc[4] = {};
    #pragma unroll 4
    for (int kt = 0; kt < 16; ++kt){
        float4 f0 = ap4[kt*8], f1 = ap4[kt*8+1];
        float v[8] = {f0.x,f0.y,f0.z,f0.w,f1.x,f1.y,f1.z,f1.w};
        short8 ahi, alo;
        #pragma unroll
        for (int j = 0; j < 8; ++j){
            union { float f; unsigned u; } t; t.f = v[j];
            ahi[j] = (short)(t.u >> 16);                   // truncation split for hi
            union { unsigned u; float f; } th; th.u = t.u & 0xffff0000u;
            alo[j] = f2bf(v[j] - th.f);
        }
        #pragma unroll
        for (int ct = 0; ct < 4; ++ct){
            const short* wb = Whi + (size_t)(ct*16+m)*512 + kt*32 + q*8;
            const short* wl = Wlo + (size_t)(ct*16+m)*512 + kt*32 + q*8;
            short8 bhi = *(const short8*)wb;
            short8 blo = *(const short8*)wl;
            acc[ct] = __builtin_amdgcn_mfma_f32_16x16x32_bf16(ahi, bhi, acc[ct], 0, 0, 0);
            acc[ct] = __builtin_amdgcn_mfma_f32_16x16x32_bf16(ahi, blo, acc[ct], 0, 0, 0);
            acc[ct] = __builtin_amdgcn_mfma_f32_16x16x32_bf16(alo, bhi, acc[ct], 0, 0, 0);
        }
    }
    // h1 store (bf16) + fused alpha: as1/ad1[row*8+head] from fp32 acc.
    #pragma unroll
    for (int ct = 0; ct < 4; ++ct){
        int col = ct*16 + m;
        float asc = aS1[col], adc = aD1[col];
        #pragma unroll
        for (int r = 0; r < 4; ++r){
            int row = rowbase + q*4 + r;                   // C/D: col=lane&15, row=quad*4+reg
            if (row < N) h1b[(size_t)row*64 + col] = f2bf(acc[ct][r]);
            float vs = acc[ct][r]*asc, vd = acc[ct][r]*adc;
            vs += __shfl_xor(vs, 1, 64); vd += __shfl_xor(vd, 1, 64);
            vs += __shfl_xor(vs, 2, 64); vd += __shfl_xor(vd, 2, 64);
            vs += __shfl_xor(vs, 4, 64); vd += __shfl_xor(vd, 4, 64);
            if ((m & 7) == 0 && row < N){
                int head = ct*2 + (m >> 3);
                as1[row*8 + head] = vs;
                ad1[row*8 + head] = vd;
            }
        }
    }
}

// ---------- bucket histogram (LDS-aggregated), bucket = dst>>7 ----------
__global__ __launch_bounds__(256) void hist_bucket(const int* __restrict__ ei,
        const int* __restrict__ flag, int* __restrict__ bcnt, int E, int Etot, int NB){
    extern __shared__ int lc[];
    for (int i = threadIdx.x; i < NB; i += 256) lc[i] = 0;
    __syncthreads();
    int f = flag[0] ? 1 : 0;
    for (int e = blockIdx.x*256 + threadIdx.x; e < Etot; e += gridDim.x*256){
        int dst = (e < E) ? ei[((size_t)(E + e)) << f] : (e - E);
        int b = dst >> 7;
        if ((unsigned)b < (unsigned)NB) atomicAdd(&lc[b], 1);   // clamp: no LDS OOB
    }
    __syncthreads();
    for (int i = threadIdx.x; i < NB; i += 256){
        int v = lc[i];
        if (v) atomicAdd(&bcnt[i], v);
    }
}

// ---------- bucket scan (single block, chunked Hillis-Steele) ----------
__global__ __launch_bounds__(1024) void scan_buckets(const int* __restrict__ bcnt,
        int* __restrict__ boffs, int* __restrict__ bcur, int NB){
    __shared__ int s[1024];
    int t = threadIdx.x;
    int chunk = (NB + 1023) >> 10;
    int lo = t*chunk; if (lo > NB) lo = NB;
    int hi = lo + chunk; if (hi > NB) hi = NB;
    int sum = 0;
    for (int i = lo; i < hi; ++i) sum += bcnt[i];
    s[t] = sum; __syncthreads();
    for (int off = 1; off < 1024; off <<= 1){
        int v = (t >= off) ? s[t-off] : 0;
        __syncthreads();
        s[t] += v;
        __syncthreads();
    }
    int run = s[t] - sum;                                   // exclusive prefix of this chunk
    for (int i = lo; i < hi; ++i){ int v = bcnt[i]; boffs[i] = run; bcur[i] = run; run += v; }
    if (t == 1023) boffs[NB] = s[1023];                     // grand total
}

// ---------- scatter edges to bucket-major tmp (dense per-bucket fill) ----------
__global__ void scatter_bucket(const int* __restrict__ ei, const int* __restrict__ flag,
        int* __restrict__ bcur, int2* __restrict__ tmp, int E, int Etot, int NB){
    int e = blockIdx.x*blockDim.x + threadIdx.x;
    if (e >= Etot) return;
    int f = flag[0] ? 1 : 0;
    int src, dst;
    if (e < E){ src = ei[((size_t)e) << f]; dst = ei[((size_t)(E + e)) << f]; }
    else      { src = dst = e - E; }
    int b = dst >> 7;
    if ((unsigned)b >= (unsigned)NB) b = NB - 1;            // clamp
    int p = atomicAdd(&bcur[b], 1);
    if ((unsigned)p < (unsigned)Etot)                       // clamp: no OOB write
        tmp[p] = make_int2(src, dst);
}

// ---------- per-bucket CSR build: LDS histogram + scan + cursors ----------
__global__ __launch_bounds__(256) void build_csr(const int2* __restrict__ tmp,
        const int* __restrict__ boffs, int* __restrict__ offs, int* __restrict__ degg,
        int* __restrict__ csr, int N, int Etot){
    __shared__ int deg[128], cur[128];
    int b = blockIdx.x, t = threadIdx.x;
    int d0 = b << 7;
    int nd = N - d0; if (nd > 128) nd = 128;
    int bo = boffs[b];
    if (bo < 0) bo = 0; if (bo > Etot) bo = Etot;           // clamp
    int cnt = boffs[b+1] - bo;
    if (cnt < 0) cnt = 0; if (cnt > Etot - bo) cnt = Etot - bo;  // clamp
    if (t < 128) deg[t] = 0;
    __syncthreads();
    for (int i = t; i < cnt; i += 256){
        int idx = tmp[bo+i].y - d0;
        if ((unsigned)idx < 128u) atomicAdd(&deg[idx], 1);  // clamp: no LDS OOB
    }
    __syncthreads();
    if (t < 128) cur[t] = deg[t];
    __syncthreads();
    for (int off = 1; off < 128; off <<= 1){                // inclusive scan
        int v = (t < 128 && t >= off) ? cur[t-off] : 0;
        __syncthreads();
        if (t < 128) cur[t] += v;
        __syncthreads();
    }
    int excl = (t < 128) ? (cur[t] - deg[t]) : 0;
    if (t < nd){
        offs[d0+t] = bo + excl;
        degg[d0+t] = deg[t];
    }
    __syncthreads();
    if (t < 128) cur[t] = bo + excl;                        // global cursor
    __syncthreads();
    for (int i = t; i < cnt; i += 256){
        int2 e = tmp[bo+i];
        int idx = e.y - d0;
        if ((unsigned)idx < 128u){
            int p = atomicAdd(&cur[idx], 1);
            if ((unsigned)p < (unsigned)Etot) csr[p] = e.x; // clamp: no OOB write
        }
    }
}

// ---------- layer-1 aggregate: wave/dst, 8x pipelined, bf16 gather ----------
__global__ __launch_bounds__(256) void agg1(const short* __restrict__ h1b,
        const float* __restrict__ as1, const float* __restrict__ ad1,
        const int* __restrict__ offs, const int* __restrict__ deg, const int* __restrict__ csr,
        const float* __restrict__ b1, short* __restrict__ x1b, int N){
    int w = blockIdx.x*4 + (threadIdx.x >> 6);
    if (w >= N) return;
    int lane = threadIdx.x & 63, h = lane >> 3;
    int s0 = offs[w], d = deg[w];
    float ad = ad1[w*8 + h];
    float l = 0.f, acc = 0.f;
    int i = 0;
    for (; i + 8 <= d; i += 8){
        int ss[8]; float ee[8], vv[8];
        #pragma unroll
        for (int j = 0; j < 8; ++j){
            int s = csr[s0+i+j];
            ss[j] = ((unsigned)s < (unsigned)N) ? s : 0;    // clamp: no OOB gather
        }
        #pragma unroll
        for (int j = 0; j < 8; ++j) ee[j] = as1[ss[j]*8 + h];
        #pragma unroll
        for (int j = 0; j < 8; ++j) vv[j] = bf2f(h1b[(size_t)ss[j]*64 + lane]);
        #pragma unroll
        for (int j = 0; j < 8; ++j){
            float e = ee[j] + ad;
            e = (e > 0.f) ? e : NEG_SLOPE*e;
            float p = __expf(e);
            l += p;
            acc = fmaf(p, vv[j], acc);
        }
    }
    for (; i < d; ++i){
        int s = csr[s0 + i];
        if ((unsigned)s >= (unsigned)N) s = 0;
        float e = as1[s*8 + h] + ad;
        e = (e > 0.f) ? e : NEG_SLOPE*e;
        float p = __expf(e);
        l += p;
        acc = fmaf(p, bf2f(h1b[(size_t)s*64 + lane]), acc);
    }
    float o = acc/(l + 1e-16f) + b1[lane];
    o = (o > 0.f) ? o : (__expf(o) - 1.f);                  // ELU
    x1b[(size_t)w*64 + lane] = f2bf(o);
}

// ---------- layer-2 GEMM fused with alpha2: wave/node; fp32 logit path ----------
__global__ __launch_bounds__(256) void gemm2a(const short* __restrict__ x1b,
        const float* __restrict__ W2, const float* __restrict__ aS2, const float* __restrict__ aD2,
        short* __restrict__ h2b, float* __restrict__ as2, float* __restrict__ ad2, int N){
    __shared__ float w2s[64*40];                            // 10,240 B
    __shared__ float xs[4][64];
    int tid = threadIdx.x;
    for (int i = tid; i < 64*40; i += 256) w2s[i] = W2[i];  // W2 [64][40] row-major
    int wv = tid >> 6, lane = tid & 63;
    int n = blockIdx.x*4 + wv;
    bool valid = n < N;
    if (valid && lane < 16){
        short4v xv = *(const short4v*)&x1b[(size_t)n*64 + lane*4];
        xs[wv][lane*4+0] = bf2f(xv[0]);
        xs[wv][lane*4+1] = bf2f(xv[1]);
        xs[wv][lane*4+2] = bf2f(xv[2]);
        xs[wv][lane*4+3] = bf2f(xv[3]);
    }
    __syncthreads();
    int c = (lane < 40) ? lane : 39;
    float acc = 0.f;
    #pragma unroll 8
    for (int k = 0; k < 64; ++k)
        acc = fmaf(xs[wv][k], w2s[k*40 + c], acc);
    float s = (lane < 40) ? acc * aS2[lane] : 0.f;
    float d = (lane < 40) ? acc * aD2[lane] : 0.f;
    #pragma unroll
    for (int off = 32; off > 0; off >>= 1){ s += __shfl_down(s, off, 64); d += __shfl_down(d, off, 64); }
    if (valid){
        if (lane < 40) h2b[(size_t)n*40 + lane] = f2bf(acc);
        if (lane == 0){ as2[n] = s; ad2[n] = d; }
    }
}

// ---------- layer-2 aggregate: wave/dst, 8x pipelined, bf16 gather ----------
__global__ __launch_bounds__(256) void agg2(const short* __restrict__ h2b,
        const float* __restrict__ as2, const float* __restrict__ ad2,
        const int* __restrict__ offs, const int* __restrict__ deg, const int* __restrict__ csr,
        const float* __restrict__ b2, float* __restrict__ out, int N){
    int w = blockIdx.x*4 + (threadIdx.x >> 6);
    if (w >= N) return;
    int lane = threadIdx.x & 63;
    int c = (lane < 40) ? lane : 0;                          // clamp: in-bounds loads
    int s0 = offs[w], d = deg[w];
    float ad = ad2[w];
    float l = 0.f, acc = 0.f;
    int i = 0;
    for (; i + 8 <= d; i += 8){
        int ss[8]; float ee[8], vv[8];
        #pragma unroll
        for (int j = 0; j < 8; ++j){
            int s = csr[s0+i+j];
            ss[j] = ((unsigned)s < (unsigned)N) ? s : 0;    // clamp: no OOB gather
        }
        #pragma unroll
        for (int j = 0; j < 8; ++j) ee[j] = as2[ss[j]];
        #pragma unroll
        for (int j = 0; j < 8; ++j) vv[j] = bf2f(h2b[(size_t)ss[j]*40 + c]);
        #pragma unroll
        for (int j = 0; j < 8; ++j){
            float e = ee[j] + ad;
            e = (e > 0.f) ? e : NEG_SLOPE*e;
            float p = __expf(e);
            l += p;
            acc = fmaf(p, vv[j], acc);
        }
    }
    for (; i < d; ++i){
        int s = csr[s0 + i];
        if ((unsigned)s >= (unsigned)N) s = 0;
        float e = as2[s] + ad;
        e = (e > 0.f) ? e : NEG_SLOPE*e;
        float p = __expf(e);
        l += p;
        acc = fmaf(p, bf2f(h2b[(size_t)s*40 + c]), acc);
    }
    if (lane < 40) out[(size_t)w*40 + lane] = acc/(l + 1e-16f) + b2[lane];
}

extern "C" void kernel_launch(void* const* d_in, const int* in_sizes, int n_in,
                              void* d_out, int out_size, void* d_ws, size_t ws_size,
                              hipStream_t stream) {
    const float* x    = (const float*)d_in[0];
    const int*   ei   = (const int*)d_in[1];
    const float* W1   = (const float*)d_in[2];
    const float* aS1  = (const float*)d_in[3];
    const float* aD1  = (const float*)d_in[4];
    const float* b1   = (const float*)d_in[5];
    const float* W2   = (const float*)d_in[6];
    const float* aS2  = (const float*)d_in[7];
    const float* aD2  = (const float*)d_in[8];
    const float* b2   = (const float*)d_in[9];
    float* out = (float*)d_out;

    const int N    = in_sizes[0] / 512;
    const int E    = in_sizes[1] / 2;
    const int Etot = E + N;
    const int NB   = (N + 127) >> 7;                       // buckets of 128 dsts

    // workspace carve (256B aligned): ~82 MB total (R2 ran with ~89 MB => fits)
    char* p = (char*)d_ws;
    auto carve = [&](size_t bytes)->char*{ char* q = p; p += ((bytes + 255) & ~(size_t)255); return q; };
    short* h1b   = (short*)carve((size_t)N*64*2);
    short* x1b   = (short*)carve((size_t)N*64*2);
    short* h2b   = (short*)carve((size_t)N*40*2);
    float* as1   = (float*)carve((size_t)N*8*4);
    float* ad1   = (float*)carve((size_t)N*8*4);
    float* as2   = (float*)carve((size_t)N*4);
    float* ad2   = (float*)carve((size_t)N*4);
    int*   deg   = (int*)carve((size_t)N*4);
    int*   offs  = (int*)carve((size_t)N*4);
    int*   bcnt  = (int*)carve((size_t)NB*4);
    int*   boffs = (int*)carve((size_t)(NB+1)*4);
    int*   bcur  = (int*)carve((size_t)NB*4);
    int*   flag  = (int*)carve(256);
    short* Whi   = (short*)carve(64*512*2);
    short* Wlo   = (short*)carve(64*512*2);
    int*   csr   = (int*)carve((size_t)Etot*4);
    int2*  tmp   = (int2*)carve((size_t)Etot*8);

    hipMemsetAsync(bcnt, 0, (size_t)NB*4, stream);

    detect_i64<<<1, 1024, 0, stream>>>(ei, flag, E);
    pack_w1<<<(64*512 + 255)/256, 256, 0, stream>>>(W1, Whi, Wlo);

    gemm1<<<(N + 63)/64, 256, 0, stream>>>(x, Whi, Wlo, aS1, aD1, h1b, as1, ad1, N);

    hist_bucket  <<<1024, 256, NB*4, stream>>>(ei, flag, bcnt, E, Etot, NB);
    scan_buckets <<<1, 1024, 0, stream>>>(bcnt, boffs, bcur, NB);
    scatter_bucket<<<(Etot + 255)/256, 256, 0, stream>>>(ei, flag, bcur, tmp, E, Etot, NB);
    build_csr    <<<NB, 256, 0, stream>>>(tmp, boffs, offs, deg, csr, N, Etot);

    agg1  <<<(N + 3)/4,  256, 0, stream>>>(h1b, as1, ad1, offs, deg, csr, b1, x1b, N);
    gemm2a<<<(N + 3)/4,  256, 0, stream>>>(x1b, W2, aS2, aD2, h2b, as2, ad2, N);
    agg2  <<<(N + 3)/4,  256, 0, stream>>>(h2b, as2, ad2, offs, deg, csr, b2, out, N);
}